// Round 4
// baseline (633.125 us; speedup 1.0000x reference)
//
#include <hip/hip_runtime.h>

typedef __attribute__((ext_vector_type(4))) float f32x4;
typedef __attribute__((ext_vector_type(8))) short short8;

// dims: B=8, S=4096, DIN=1024, DH=1024; M=32768, N=2048 (paired-permuted), K=1024
#define NCHUNK 64
#define CLEN 64

__device__ __forceinline__ unsigned short f2bf(float f) {
    union { float f; unsigned int u; } a; a.f = f;
    unsigned int r = a.u + 0x7fffu + ((a.u >> 16) & 1u);   // RTNE (finite)
    return (unsigned short)(r >> 16);
}
__device__ __forceinline__ float bf2f(unsigned short u) {
    union { unsigned int u; float f; } a; a.u = ((unsigned int)u) << 16;
    return a.f;
}

// ---------------- x: f32 -> bf16 (vectorized, grid-stride) ----------------
__global__ __launch_bounds__(256) void conv_bf16(const float* __restrict__ in,
                                                 unsigned short* __restrict__ out, int n4) {
    int stride = gridDim.x * 256;
    for (int i = blockIdx.x * 256 + threadIdx.x; i < n4; i += stride) {
        float4 v = reinterpret_cast<const float4*>(in)[i];
        ushort4 o;
        o.x = f2bf(v.x); o.y = f2bf(v.y); o.z = f2bf(v.z); o.w = f2bf(v.w);
        reinterpret_cast<ushort4*>(out)[i] = o;
    }
}

// ---------------- W: f32 -> bf16 with channel-pair permutation ----------------
__global__ __launch_bounds__(256) void conv_w_perm(const float* __restrict__ in,
                                                   unsigned short* __restrict__ out) {
    int i = blockIdx.x * 256 + threadIdx.x;       // float4 groups; 524288 total
    int r = i >> 8, c4 = i & 255;
    float4 v = reinterpret_cast<const float4*>(in)[i];
    int rp;
    if (r < 1024) { rp = (r >> 7) * 256 + (r & 127); }
    else { int ch = r - 1024; rp = (ch >> 7) * 256 + 128 + (ch & 127); }
    ushort4 o;
    o.x = f2bf(v.x); o.y = f2bf(v.y); o.z = f2bf(v.z); o.w = f2bf(v.w);
    reinterpret_cast<ushort4*>(out)[rp * 256 + c4] = o;
}

// =================== GEMM: 256x256 tile, BK=64, m201 8-phase template ===============
// LDS slots (2): slot s @ s*65536:  A-ks0 @+0, A-ks1 @+16384, B-ks0 @+32768, B-ks1 @+49152
// Stage units per K-tile, order: u0=B-ks0, u1=A-ks0, u2=B-ks1, u3=A-ks1 (2 gload_lds each)

#define STAGEU(T, U) { \
    const unsigned short* _g = (((U) & 1) ? gA : gB) + (T) * 64 + ((U) >> 1) * 32; \
    char* _d = ldsb + ((T) & 1) * 65536 + (((U) & 1) ? 0 : 32768) + ((U) >> 1) * 16384 + sdst; \
    __builtin_amdgcn_global_load_lds((const __attribute__((address_space(1))) unsigned int*)_g, \
        (__attribute__((address_space(3))) unsigned int*)_d, 16, 0, 0); \
    __builtin_amdgcn_global_load_lds((const __attribute__((address_space(1))) unsigned int*)(_g + 131072), \
        (__attribute__((address_space(3))) unsigned int*)(_d + 8192), 16, 0, 0); }

#define LDA4(SLOT, KS, MIH) { \
    const char* _p = ldsb + (SLOT) * 65536 + (KS) * 16384 + aoff + (MIH) * 4096; \
    af[0] = *(const short8*)(_p);        af[1] = *(const short8*)(_p + 1024); \
    af[2] = *(const short8*)(_p + 2048); af[3] = *(const short8*)(_p + 3072); }

#define LDB4(SLOT, KS) { \
    const char* _p = ldsb + (SLOT) * 65536 + 32768 + (KS) * 16384 + boff; \
    bf[0] = *(const short8*)(_p);        bf[1] = *(const short8*)(_p + 1024); \
    bf[2] = *(const short8*)(_p + 2048); bf[3] = *(const short8*)(_p + 3072); }

template<int MIH>
__device__ __forceinline__ void mfma16(f32x4 (&acc)[8][4], const short8 (&af)[4], const short8 (&bf)[4]) {
#pragma unroll
    for (int m = 0; m < 4; ++m)
#pragma unroll
        for (int n = 0; n < 4; ++n)
            acc[MIH * 4 + m][n] = __builtin_amdgcn_mfma_f32_16x16x32_bf16(af[m], bf[n], acc[MIH * 4 + m][n], 0, 0, 0);
}

#define PHASE(TC, KS, MIH, DOB, STG, VMS) { \
    LDA4((TC) & 1, KS, MIH); \
    if (DOB) LDB4((TC) & 1, KS); \
    STG; \
    __builtin_amdgcn_s_barrier(); \
    asm volatile("s_waitcnt lgkmcnt(0)" ::: "memory"); \
    __builtin_amdgcn_sched_barrier(0); \
    __builtin_amdgcn_s_setprio(1); \
    mfma16<(MIH)>(acc, af, bf); \
    __builtin_amdgcn_s_setprio(0); \
    __builtin_amdgcn_sched_barrier(0); \
    VMS; \
    __builtin_amdgcn_s_barrier(); }

__global__ __launch_bounds__(512, 2) void gemm_fused(
    const unsigned short* __restrict__ xb, const unsigned short* __restrict__ wbP,
    const float* __restrict__ bias,
    unsigned int* __restrict__ CVg, float* __restrict__ CCc, float* __restrict__ CVc)
{
    __shared__ char lds[131072];
    char* ldsb = lds;
    const int bid = blockIdx.x;
    const int swz = (bid & 7) * 128 + (bid >> 3);  // XCD-contiguous logical tiles (1024 % 8 == 0)
    const int nt = swz & 7, mt = swz >> 3;
    const int m0 = mt * 256, chBase = nt * 128, n0p = nt * 256;
    const int t = threadIdx.x;
    const int w = t >> 6, l = t & 63;
    const int wm = w >> 2, wn = w & 3;
    const int wr = wm * 128, wc = wn * 64;

    // staging: linear LDS dest (t*16), source pre-swizzled: 16B-block ^= ((t>>5)&1)<<1
    const int blk = (t & 3) ^ (((t >> 5) & 1) << 1);
    const int srow = t >> 2;
    const unsigned short* gA = xb  + (size_t)(m0 + srow)  * 1024 + blk * 8;
    const unsigned short* gB = wbP + (size_t)(n0p + srow) * 1024 + blk * 8;
    const int sdst = t * 16;

    // frag read addressing: row*64 bytes + (16B-slot ^ row-bit3 swizzle); row&8 == l&8
    const int swzl = ((l >> 4) << 4) ^ ((l & 8) << 2);
    const int aoff = (wm * 128 + (l & 15)) * 64 + swzl;   // + slot*65536 + ks*16384 + mi*1024
    const int boff = (wn * 64  + (l & 15)) * 64 + swzl;   // + slot*65536 + 32768 + ks*16384 + ni*1024

    f32x4 acc[8][4];
#pragma unroll
    for (int i = 0; i < 8; ++i)
#pragma unroll
        for (int j = 0; j < 4; ++j) acc[i][j] = (f32x4){0.f, 0.f, 0.f, 0.f};

    short8 af[4], bf[4];

    // prologue: tile0 all 4 units + tile1 first 3 units -> 14 loads, keep 6 (tile0 landed)
    STAGEU(0, 0); STAGEU(0, 1); STAGEU(0, 2); STAGEU(0, 3);
    STAGEU(1, 0); STAGEU(1, 1); STAGEU(1, 2);
    asm volatile("s_waitcnt vmcnt(6)" ::: "memory");
    __builtin_amdgcn_sched_barrier(0);
    __builtin_amdgcn_s_barrier();

#pragma unroll 8
    for (int i = 0; i < 8; ++i) {
        const int t0 = 2 * i, t1 = 2 * i + 1;
        const bool s2 = (i < 7);   // stage tiles t0+2 / t0+3 only if they exist
        // ---- tile t0 (slot 0) ----
        PHASE(t0, 0, 0, 1, STAGEU(t1, 3), ((void)0));
        PHASE(t0, 0, 1, 0, if (s2) STAGEU(t0 + 2, 0), ((void)0));
        PHASE(t0, 1, 0, 1, if (s2) STAGEU(t0 + 2, 1), ((void)0));
        PHASE(t0, 1, 1, 0, if (s2) STAGEU(t0 + 2, 2),
              if (s2) { asm volatile("s_waitcnt vmcnt(6)" ::: "memory"); }
              else    { asm volatile("s_waitcnt vmcnt(0)" ::: "memory"); });
        // ---- tile t1 (slot 1) ----
        PHASE(t1, 0, 0, 1, if (s2) STAGEU(t0 + 2, 3), ((void)0));
        PHASE(t1, 0, 1, 0, if (s2) STAGEU(t0 + 3, 0), ((void)0));
        PHASE(t1, 1, 0, 1, if (s2) STAGEU(t0 + 3, 1), ((void)0));
        PHASE(t1, 1, 1, 0, if (s2) STAGEU(t0 + 3, 2),
              if (s2) { asm volatile("s_waitcnt vmcnt(6)" ::: "memory"); });
    }

    // ---------- epilogue: activation -> LDS z/g exchange -> packed CV + chunk carries ----------
    const bool isGate = (wc < 128);
    float bv[4];
#pragma unroll
    for (int ni = 0; ni < 4; ++ni) {
        int j = wc + ni * 16 + (l & 15);
        bv[ni] = bias[isGate ? (chBase + j) : (1024 + chBase + (j - 128))];
    }
    const int slotw = (wr != 0);
#pragma unroll
    for (int p = 0; p < 2; ++p) {       // UNROLLED: keeps acc indices static (no scratch spill)
        if (p) __syncthreads();
#pragma unroll
        for (int q = 0; q < 4; ++q) {   // mi = 4*p + q, static
#pragma unroll
            for (int ni = 0; ni < 4; ++ni) {
#pragma unroll
                for (int r = 0; r < 4; ++r) {
                    float v = acc[4 * p + q][ni][r] + bv[ni];
                    float o = isGate ? (1.f / (1.f + __expf(-v)))
                                     : ((v >= 0.f) ? (v + 0.5f) : (1.f / (1.f + __expf(-v))));
                    int rr = q * 16 + ((l >> 4) << 2) + r;     // [0,64)
                    int j = wc + ni * 16 + (l & 15);
                    unsigned short* zb = (unsigned short*)lds + slotw * 16384;
                    if (isGate) zb[rr * 128 + j] = f2bf(o);
                    else        zb[8192 + rr * 128 + (j - 128)] = f2bf(o);
                }
            }
        }
        __syncthreads();
        {
            int slot = t >> 8;                    // 0/1: chunk p / chunk 2+p
            int tt = t & 255;
            int cglob = (slot ? 2 : 0) + p;
            int mrow0 = m0 + cglob * 64;
            const unsigned short* zb = (const unsigned short*)lds + slot * 16384;
            const unsigned short* gb = zb + 8192;
            int ch = tt & 127, half = tt >> 7;
#pragma unroll 4
            for (int i = 0; i < 32; ++i) {
                int rr = half * 32 + i;
                float z = bf2f(zb[rr * 128 + ch]);
                float gg = bf2f(gb[rr * 128 + ch]);
                unsigned short cb = f2bf(1.f - z);
                unsigned short vb = f2bf(z * gg);
                CVg[(size_t)(mrow0 + rr) * 1024 + chBase + ch] =
                    (unsigned int)cb | ((unsigned int)vb << 16);
            }
            if (tt < 128) {                       // per-channel chunk carry (rounded c,v chain)
                float C = 1.f, V = 0.f;
#pragma unroll 8
                for (int i = 0; i < 64; ++i) {
                    float z = bf2f(zb[i * 128 + tt]);
                    float gg = bf2f(gb[i * 128 + tt]);
                    float c = bf2f(f2bf(1.f - z));
                    float vv = bf2f(f2bf(z * gg));
                    C *= c; V = c * V + vv;
                }
                int b = mrow0 >> 12, ck = (mrow0 >> 6) & 63;
                CCc[(size_t)(b * 64 + ck) * 1024 + chBase + tt] = C;
                CVc[(size_t)(b * 64 + ck) * 1024 + chBase + tt] = V;
            }
        }
    }
}

// ---------------- scan pass 2: sequential scan over 64 chunk carries --------------
__global__ __launch_bounds__(256) void scan_prefix(
    const float* __restrict__ CC, const float* __restrict__ CV,
    const float* __restrict__ h0, float* __restrict__ Hinit)
{
    int g = blockIdx.x * 256 + threadIdx.x;   // 8192 threads
    int h = g & 1023, b = g >> 10;
    float hc = h0[b * 1024 + h];
#pragma unroll 8
    for (int ck = 0; ck < NCHUNK; ++ck) {
        int idx = (b * 64 + ck) * 1024 + h;
        Hinit[idx] = hc;
        hc = CC[idx] * hc + CV[idx];
    }
}

// ---------------- scan pass 3: apply within chunk from packed CV ------------------
__global__ __launch_bounds__(256) void scan_apply(
    const unsigned int* __restrict__ CVg, const float* __restrict__ Hinit,
    float* __restrict__ out)
{
    int g = blockIdx.x * 256 + threadIdx.x;   // 524288
    int ch = g & 1023, ck = (g >> 10) & 63, b = g >> 16;
    int mbase = b * 4096 + ck * CLEN;
    const unsigned int* pc = CVg + (size_t)mbase * 1024 + ch;
    float h = Hinit[g];
    float* po = out + (size_t)mbase * 1024 + ch;
#pragma unroll 8
    for (int i = 0; i < CLEN; ++i) {
        unsigned int u = pc[i * 1024];
        h = bf2f((unsigned short)(u & 0xffff)) * h + bf2f((unsigned short)(u >> 16));
        po[i * 1024] = h;
    }
}

extern "C" void kernel_launch(void* const* d_in, const int* in_sizes, int n_in,
                              void* d_out, int out_size, void* d_ws, size_t ws_size,
                              hipStream_t stream)
{
    const float* x    = (const float*)d_in[0];   // (8,4096,1024)
    const float* h0   = (const float*)d_in[1];   // (8,1,1024)
    const float* W    = (const float*)d_in[2];   // (2048,1024)
    const float* bias = (const float*)d_in[3];   // (2048,)
    float* out = (float*)d_out;

    unsigned short* xb = (unsigned short*)d_out;                    // 67MB staged in d_out
    unsigned short* wbP = (unsigned short*)d_ws;                    // 4MB permuted W bf16
    unsigned int* CVg = (unsigned int*)((char*)d_ws + 4194304);     // 134MB packed (c,v)
    float* CCc   = (float*)((char*)d_ws + 138412032);               // 2MB
    float* CVc   = (float*)((char*)d_ws + 140509184);               // 2MB
    float* Hinit = (float*)((char*)d_ws + 142606336);               // 2MB

    conv_bf16<<<2048, 256, 0, stream>>>(x, xb, 8388608);
    conv_w_perm<<<2048, 256, 0, stream>>>(W, wbP);
    gemm_fused<<<1024, 512, 0, stream>>>(xb, wbP, bias, CVg, CCc, CVc);
    scan_prefix<<<32, 256, 0, stream>>>(CCc, CVc, h0, Hinit);
    scan_apply<<<2048, 256, 0, stream>>>(CVg, Hinit, out);
}

// Round 5
// 488.760 us; speedup vs baseline: 1.2954x; 1.2954x over previous
//
#include <hip/hip_runtime.h>

typedef __attribute__((ext_vector_type(4))) float f32x4;
typedef __attribute__((ext_vector_type(8))) short short8;

// dims: B=8, S=4096, DIN=1024, DH=1024; M=32768, N=2048(ch-interleaved), K=1024
#define NCHUNK 64
#define CLEN 64

__device__ __forceinline__ unsigned short f2bf(float f) {
    union { float f; unsigned int u; } a; a.f = f;
    unsigned int r = a.u + 0x7fffu + ((a.u >> 16) & 1u);   // RTNE (finite)
    return (unsigned short)(r >> 16);
}
__device__ __forceinline__ float bf2f(unsigned short u) {
    union { unsigned int u; float f; } a; a.u = ((unsigned int)u) << 16;
    return a.f;
}

// ---------- conv: x f32->bf16 (blocks 0..2047) + W f32->bf16 interleave-perm (2048..2559) ----
// wbP row (g*128 + i): i<64 -> W row g*64+i (gate ch g*64+i), i>=64 -> W row 1024+g*64+(i-64)
__global__ __launch_bounds__(256) void conv_all(const float* __restrict__ x,
                                                const float* __restrict__ W,
                                                unsigned short* __restrict__ xb,
                                                unsigned short* __restrict__ wbP) {
    int bid = blockIdx.x, t = threadIdx.x;
    if (bid < 2048) {
        for (int i = bid * 256 + t; i < 8388608; i += 524288) {
            float4 v = reinterpret_cast<const float4*>(x)[i];
            ushort4 o;
            o.x = f2bf(v.x); o.y = f2bf(v.y); o.z = f2bf(v.z); o.w = f2bf(v.w);
            reinterpret_cast<ushort4*>(xb)[i] = o;
        }
    } else {
        int base = (bid - 2048) * 256 + t;
#pragma unroll
        for (int k = 0; k < 4; ++k) {
            int i = base + k * 131072;                 // 524288 float4 total
            int r = i >> 8, c4 = i & 255;
            float4 v = reinterpret_cast<const float4*>(W)[i];
            int rp;
            if (r < 1024) rp = (r >> 6) * 128 + (r & 63);
            else { int c = r - 1024; rp = (c >> 6) * 128 + 64 + (c & 63); }
            ushort4 o;
            o.x = f2bf(v.x); o.y = f2bf(v.y); o.z = f2bf(v.z); o.w = f2bf(v.w);
            reinterpret_cast<ushort4*>(wbP)[rp * 256 + c4] = o;
        }
    }
}

// =========== GEMM 128x128 tile, BK=64, proven 2-phase skeleton + XOR swizzle ===========
// A = xb (M x K), B = wbP (2048 x K, ch-interleaved). 256 thr = 4 waves (2M x 2N).
// LDS 32KB single-buffer; reused by epilogue for z/g exchange.
__global__ __launch_bounds__(256) void gemm_fused(
    const unsigned short* __restrict__ xb, const unsigned short* __restrict__ wbP,
    const float* __restrict__ bias,
    unsigned int* __restrict__ CVg, float* __restrict__ CCc, float* __restrict__ CVc)
{
    __shared__ unsigned short sm[16384];          // A: el [0,8192), B: el [8192,16384)
    const int bid = blockIdx.x;
    const int swz = (bid & 7) * 512 + (bid >> 3); // XCD-contiguous (4096 % 8 == 0, bijective)
    const int nt = swz & 15, mt = swz >> 4;
    const int m0 = mt * 128, chBase = nt * 64, n0p = nt * 128;
    const int t = threadIdx.x;
    const int w = t >> 6, l = t & 63;
    const int wr = (w >> 1) * 64, wc = (w & 1) * 64;

    // staging: linear LDS dest (t*16 + j*4096 bytes); LDS[row][slot] holds global block slot^(row&7)
    // so source block = (t&7) ^ ((t>>3)&7)   [row = j*32 + (t>>3), j*32 ≡ 0 mod 8]
    const int srow = t >> 3;
    const int sblk = (t & 7) ^ (srow & 7);
    const unsigned short* gA = xb  + (size_t)(m0 + srow)  * 1024 + sblk * 8;
    const unsigned short* gB = wbP + (size_t)(n0p + srow) * 1024 + sblk * 8;

    f32x4 acc[4][4];
#pragma unroll
    for (int i = 0; i < 4; ++i)
#pragma unroll
        for (int j = 0; j < 4; ++j) acc[i][j] = (f32x4){0.f, 0.f, 0.f, 0.f};

    for (int kt = 0; kt < 16; ++kt) {
        __syncthreads();                          // prior reads done before overwrite
        const unsigned short* a = gA + kt * 64;
        const unsigned short* b = gB + kt * 64;
#pragma unroll
        for (int j = 0; j < 4; ++j) {
            __builtin_amdgcn_global_load_lds(
                (const __attribute__((address_space(1))) unsigned int*)(a + j * 32768),
                (__attribute__((address_space(3))) unsigned int*)
                    ((__attribute__((address_space(3))) char*)sm + t * 16 + j * 4096), 16, 0, 0);
            __builtin_amdgcn_global_load_lds(
                (const __attribute__((address_space(1))) unsigned int*)(b + j * 32768),
                (__attribute__((address_space(3))) unsigned int*)
                    ((__attribute__((address_space(3))) char*)sm + 16384 + t * 16 + j * 4096), 16, 0, 0);
        }
        asm volatile("s_waitcnt vmcnt(0)" ::: "memory");
        __syncthreads();                          // staging visible

#pragma unroll
        for (int ks = 0; ks < 2; ++ks) {
            short8 af[4], bfr[4];
#pragma unroll
            for (int mi = 0; mi < 4; ++mi) {
                int row = wr + mi * 16 + (l & 15);
                int slot = ((ks << 2) + (l >> 4)) ^ (l & 7);     // read-side swizzle
                af[mi] = *reinterpret_cast<const short8*>((const char*)sm + row * 128 + slot * 16);
            }
#pragma unroll
            for (int ni = 0; ni < 4; ++ni) {
                int row = wc + ni * 16 + (l & 15);
                int slot = ((ks << 2) + (l >> 4)) ^ (l & 7);
                bfr[ni] = *reinterpret_cast<const short8*>((const char*)sm + 16384 + row * 128 + slot * 16);
            }
#pragma unroll
            for (int mi = 0; mi < 4; ++mi)
#pragma unroll
                for (int ni = 0; ni < 4; ++ni)
                    acc[mi][ni] = __builtin_amdgcn_mfma_f32_16x16x32_bf16(af[mi], bfr[ni], acc[mi][ni], 0, 0, 0);
        }
    }

    // ---------- epilogue: activation -> LDS z/g exchange -> packed CV + chunk carries ----------
    const bool isHid = (wc != 0);
    float bv[4];
#pragma unroll
    for (int ni = 0; ni < 4; ++ni) {
        int ch = chBase + ni * 16 + (l & 15);
        bv[ni] = bias[isHid ? (1024 + ch) : ch];
    }
    __syncthreads();                              // all waves done with main-loop LDS
    {
        unsigned short* eb = sm + (w >> 1) * 8192 + (isHid ? 4096 : 0);   // chunk = w>>1
#pragma unroll
        for (int mi = 0; mi < 4; ++mi)
#pragma unroll
            for (int ni = 0; ni < 4; ++ni)
#pragma unroll
                for (int r = 0; r < 4; ++r) {
                    float v = acc[mi][ni][r] + bv[ni];
                    float o = isHid ? ((v >= 0.f) ? (v + 0.5f) : (1.f / (1.f + __expf(-v))))
                                    : (1.f / (1.f + __expf(-v)));
                    int row = mi * 16 + ((l >> 4) << 2) + r;   // [0,64) within chunk
                    int ch = ni * 16 + (l & 15);               // [0,64)
                    eb[row * 64 + ch] = f2bf(o);
                }
    }
    __syncthreads();
    {
        int chunk = t >> 7, tt = t & 127;
        const unsigned short* zb = sm + chunk * 8192;
        const unsigned short* gb = zb + 4096;
        int mrow0 = m0 + chunk * 64;
#pragma unroll 4
        for (int i = 0; i < 32; ++i) {
            int idx = i * 128 + tt;                // [0,4096)
            int row = idx >> 6, ch = idx & 63;
            float z = bf2f(zb[row * 64 + ch]);
            float gg = bf2f(gb[row * 64 + ch]);
            CVg[(size_t)(mrow0 + row) * 1024 + chBase + ch] =
                (unsigned int)f2bf(1.f - z) | ((unsigned int)f2bf(z * gg) << 16);
        }
        if (tt < 64) {                             // per-channel chunk carry (rounded c,v chain)
            float C = 1.f, V = 0.f;
#pragma unroll 8
            for (int i = 0; i < 64; ++i) {
                float z = bf2f(zb[i * 64 + tt]);
                float gg = bf2f(gb[i * 64 + tt]);
                float c = bf2f(f2bf(1.f - z));
                float vv = bf2f(f2bf(z * gg));
                C *= c; V = c * V + vv;
            }
            int b = mrow0 >> 12, ck = (mrow0 >> 6) & 63;
            CCc[(size_t)(b * 64 + ck) * 1024 + chBase + tt] = C;
            CVc[(size_t)(b * 64 + ck) * 1024 + chBase + tt] = V;
        }
    }
}

// ---------------- scan pass 2: sequential scan over 64 chunk carries --------------
__global__ __launch_bounds__(256) void scan_prefix(
    const float* __restrict__ CC, const float* __restrict__ CV,
    const float* __restrict__ h0, float* __restrict__ Hinit)
{
    int g = blockIdx.x * 256 + threadIdx.x;   // 8192 threads
    int h = g & 1023, b = g >> 10;
    float hc = h0[b * 1024 + h];
#pragma unroll 8
    for (int ck = 0; ck < NCHUNK; ++ck) {
        int idx = (b * 64 + ck) * 1024 + h;
        Hinit[idx] = hc;
        hc = CC[idx] * hc + CV[idx];
    }
}

// ---------------- scan pass 3: apply within chunk from packed CV ------------------
__global__ __launch_bounds__(256) void scan_apply(
    const unsigned int* __restrict__ CVg, const float* __restrict__ Hinit,
    float* __restrict__ out)
{
    int g = blockIdx.x * 256 + threadIdx.x;   // 524288
    int ch = g & 1023, ck = (g >> 10) & 63, b = g >> 16;
    int mbase = b * 4096 + ck * CLEN;
    const unsigned int* pc = CVg + (size_t)mbase * 1024 + ch;
    float h = Hinit[g];
    float* po = out + (size_t)mbase * 1024 + ch;
#pragma unroll 8
    for (int i = 0; i < CLEN; ++i) {
        unsigned int u = pc[i * 1024];
        h = bf2f((unsigned short)(u & 0xffff)) * h + bf2f((unsigned short)(u >> 16));
        po[i * 1024] = h;
    }
}

extern "C" void kernel_launch(void* const* d_in, const int* in_sizes, int n_in,
                              void* d_out, int out_size, void* d_ws, size_t ws_size,
                              hipStream_t stream)
{
    const float* x    = (const float*)d_in[0];   // (8,4096,1024)
    const float* h0   = (const float*)d_in[1];   // (8,1,1024)
    const float* W    = (const float*)d_in[2];   // (2048,1024)
    const float* bias = (const float*)d_in[3];   // (2048,)
    float* out = (float*)d_out;

    unsigned short* xb = (unsigned short*)d_out;                    // 67MB staged in d_out
    unsigned short* wbP = (unsigned short*)d_ws;                    // 4MB interleaved W bf16
    unsigned int* CVg = (unsigned int*)((char*)d_ws + 4194304);     // 134MB packed (c,v)
    float* CCc   = (float*)((char*)d_ws + 138412032);               // 2MB
    float* CVc   = (float*)((char*)d_ws + 140509184);               // 2MB
    float* Hinit = (float*)((char*)d_ws + 142606336);               // 2MB

    conv_all<<<2560, 256, 0, stream>>>(x, W, xb, wbP);
    gemm_fused<<<4096, 256, 0, stream>>>(xb, wbP, bias, CVg, CCc, CVc);
    scan_prefix<<<32, 256, 0, stream>>>(CCc, CVc, h0, Hinit);
    scan_apply<<<2048, 256, 0, stream>>>(CVg, Hinit, out);
}

// Round 6
// 464.359 us; speedup vs baseline: 1.3634x; 1.0525x over previous
//
#include <hip/hip_runtime.h>

typedef __attribute__((ext_vector_type(4))) float f32x4;
typedef __attribute__((ext_vector_type(8))) short short8;

// dims: B=8, S=4096, DIN=1024, DH=1024; M=32768, N=2048(ch-interleaved), K=1024
#define NCHUNK 64
#define CLEN 64

__device__ __forceinline__ unsigned short f2bf(float f) {
    union { float f; unsigned int u; } a; a.f = f;
    unsigned int r = a.u + 0x7fffu + ((a.u >> 16) & 1u);   // RTNE (finite)
    return (unsigned short)(r >> 16);
}
__device__ __forceinline__ float bf2f(unsigned short u) {
    union { unsigned int u; float f; } a; a.u = ((unsigned int)u) << 16;
    return a.f;
}

// ---------- conv: x f32->bf16 (blocks 0..2047) + W f32->bf16 interleave-perm (2048..2559) ----
__global__ __launch_bounds__(256) void conv_all(const float* __restrict__ x,
                                                const float* __restrict__ W,
                                                unsigned short* __restrict__ xb,
                                                unsigned short* __restrict__ wbP) {
    int bid = blockIdx.x, t = threadIdx.x;
    if (bid < 2048) {
        for (int i = bid * 256 + t; i < 8388608; i += 524288) {
            float4 v = reinterpret_cast<const float4*>(x)[i];
            ushort4 o;
            o.x = f2bf(v.x); o.y = f2bf(v.y); o.z = f2bf(v.z); o.w = f2bf(v.w);
            reinterpret_cast<ushort4*>(xb)[i] = o;
        }
    } else {
        int base = (bid - 2048) * 256 + t;
#pragma unroll
        for (int k = 0; k < 4; ++k) {
            int i = base + k * 131072;                 // 524288 float4 total
            int r = i >> 8, c4 = i & 255;
            float4 v = reinterpret_cast<const float4*>(W)[i];
            int rp;
            if (r < 1024) rp = (r >> 6) * 128 + (r & 63);
            else { int c = r - 1024; rp = (c >> 6) * 128 + 64 + (c & 63); }
            ushort4 o;
            o.x = f2bf(v.x); o.y = f2bf(v.y); o.z = f2bf(v.z); o.w = f2bf(v.w);
            reinterpret_cast<ushort4*>(wbP)[rp * 256 + c4] = o;
        }
    }
}

// ============ GEMM 128x128, BK=32, 3-buffer counted-vmcnt pipeline (T3/T4) ============
// A = xb (M x K), B = wbP (2048 x K, ch-interleaved). 256 thr = 4 waves (2M x 2N).
// LDS: buf i (i<3): A @ i*8192, B @ 24576 + i*8192. Epilogue reuses first 32KB.

#define GLOAD(SRC, DST) \
    __builtin_amdgcn_global_load_lds((const __attribute__((address_space(1))) unsigned int*)(SRC), \
        (__attribute__((address_space(3))) unsigned int*)(DST), 16, 0, 0)

#define STAGE(KT, BUF) { \
    const unsigned short* _a = gA + (KT) * 32; \
    const unsigned short* _b = gB + (KT) * 32; \
    char* _dA = lds + (BUF) * 8192 + t * 16; \
    char* _dB = lds + 24576 + (BUF) * 8192 + t * 16; \
    GLOAD(_a, _dA); GLOAD(_a + 65536, _dA + 4096); \
    GLOAD(_b, _dB); GLOAD(_b + 65536, _dB + 4096); }

__global__ __launch_bounds__(256) void gemm_fused(
    const unsigned short* __restrict__ xb, const unsigned short* __restrict__ wbP,
    const float* __restrict__ bias,
    unsigned int* __restrict__ CVg, float* __restrict__ CCc, float* __restrict__ CVc)
{
    __shared__ char lds[49152];
    unsigned short* sm = (unsigned short*)lds;
    const int bid = blockIdx.x;
    const int swz = (bid & 7) * 512 + (bid >> 3); // XCD-contiguous (4096 % 8 == 0, bijective)
    const int nt = swz & 15, mt = swz >> 4;
    const int m0 = mt * 128, chBase = nt * 64, n0p = nt * 128;
    const int t = threadIdx.x;
    const int w = t >> 6, l = t & 63;
    const int wr = (w >> 1) * 64, wc = (w & 1) * 64;

    // staging: linear LDS dest t*16; source block pre-swizzled: (t&3) ^ ((t>>3)&3)
    const int srow = t >> 2;
    const int sblk = (t & 3) ^ ((t >> 3) & 3);
    const unsigned short* gA = xb  + (size_t)(m0 + srow)  * 1024 + sblk * 8;
    const unsigned short* gB = wbP + (size_t)(n0p + srow) * 1024 + sblk * 8;

    // read side: byte = region + row*64 + slot*16, slot = (l>>4) ^ ((row>>1)&3); row%16 = l&15
    const int rslot = ((l >> 4) ^ ((l >> 1) & 3)) * 16;
    const int aoff = (wr + (l & 15)) * 64 + rslot;       // + buf*8192 + mi*1024
    const int boff = (wc + (l & 15)) * 64 + rslot;       // + 24576 + buf*8192 + ni*1024

    f32x4 acc[4][4];
#pragma unroll
    for (int i = 0; i < 4; ++i)
#pragma unroll
        for (int j = 0; j < 4; ++j) acc[i][j] = (f32x4){0.f, 0.f, 0.f, 0.f};

    STAGE(0, 0); STAGE(1, 1);
    asm volatile("s_waitcnt vmcnt(4)" ::: "memory");     // tile 0 landed (tile 1 in flight)
    __builtin_amdgcn_sched_barrier(0);
    __builtin_amdgcn_s_barrier();

    int rb = 0, wb = 2;
    for (int kt = 0; kt < 32; ++kt) {
        if (kt < 30) STAGE(kt + 2, wb);                  // prefetch 2 tiles ahead
        const char* bA = lds + rb * 8192;
        const char* bB = lds + 24576 + rb * 8192;
        short8 af[4], bfr[4];
#pragma unroll
        for (int mi = 0; mi < 4; ++mi) af[mi]  = *reinterpret_cast<const short8*>(bA + aoff + mi * 1024);
#pragma unroll
        for (int ni = 0; ni < 4; ++ni) bfr[ni] = *reinterpret_cast<const short8*>(bB + boff + ni * 1024);
        asm volatile("s_waitcnt lgkmcnt(0)" ::: "memory");
        __builtin_amdgcn_sched_barrier(0);
        __builtin_amdgcn_s_setprio(1);
#pragma unroll
        for (int mi = 0; mi < 4; ++mi)
#pragma unroll
            for (int ni = 0; ni < 4; ++ni)
                acc[mi][ni] = __builtin_amdgcn_mfma_f32_16x16x32_bf16(af[mi], bfr[ni], acc[mi][ni], 0, 0, 0);
        __builtin_amdgcn_s_setprio(0);
        __builtin_amdgcn_sched_barrier(0);
        if (kt < 30)       { asm volatile("s_waitcnt vmcnt(4)" ::: "memory"); }  // tile kt+1 landed
        else if (kt == 30) { asm volatile("s_waitcnt vmcnt(0)" ::: "memory"); }  // drain for kt=31
        __builtin_amdgcn_s_barrier();
        rb = (rb == 2) ? 0 : rb + 1;
        wb = (wb == 2) ? 0 : wb + 1;
    }

    // ---------- epilogue: activation -> LDS z/g exchange -> packed CV + chunk carries ----------
    const bool isHid = (wc != 0);
    float bv[4];
#pragma unroll
    for (int ni = 0; ni < 4; ++ni) {
        int ch = chBase + ni * 16 + (l & 15);
        bv[ni] = bias[isHid ? (1024 + ch) : ch];
    }
    __syncthreads();                              // all waves done with main-loop LDS
    {
        unsigned short* eb = sm + (w >> 1) * 8192 + (isHid ? 4096 : 0);   // chunk = w>>1
#pragma unroll
        for (int mi = 0; mi < 4; ++mi)
#pragma unroll
            for (int ni = 0; ni < 4; ++ni)
#pragma unroll
                for (int r = 0; r < 4; ++r) {
                    float v = acc[mi][ni][r] + bv[ni];
                    float o = isHid ? ((v >= 0.f) ? (v + 0.5f) : (1.f / (1.f + __expf(-v))))
                                    : (1.f / (1.f + __expf(-v)));
                    int row = mi * 16 + ((l >> 4) << 2) + r;   // [0,64) within chunk
                    int ch = ni * 16 + (l & 15);               // [0,64)
                    eb[row * 64 + ch] = f2bf(o);
                }
    }
    __syncthreads();
    {
        int chunk = t >> 7, tt = t & 127;
        const unsigned short* zb = sm + chunk * 8192;
        const unsigned short* gb = zb + 4096;
        int mrow0 = m0 + chunk * 64;
#pragma unroll 4
        for (int i = 0; i < 32; ++i) {
            int idx = i * 128 + tt;                // [0,4096)
            int row = idx >> 6, ch = idx & 63;
            float z = bf2f(zb[row * 64 + ch]);
            float gg = bf2f(gb[row * 64 + ch]);
            CVg[(size_t)(mrow0 + row) * 1024 + chBase + ch] =
                (unsigned int)f2bf(1.f - z) | ((unsigned int)f2bf(z * gg) << 16);
        }
        if (tt < 64) {                             // per-channel chunk carry (rounded c,v chain)
            float C = 1.f, V = 0.f;
#pragma unroll 8
            for (int i = 0; i < 64; ++i) {
                float z = bf2f(zb[i * 64 + tt]);
                float gg = bf2f(gb[i * 64 + tt]);
                float c = bf2f(f2bf(1.f - z));
                float vv = bf2f(f2bf(z * gg));
                C *= c; V = c * V + vv;
            }
            int b = mrow0 >> 12, ck = (mrow0 >> 6) & 63;
            CCc[(size_t)(b * 64 + ck) * 1024 + chBase + tt] = C;
            CVc[(size_t)(b * 64 + ck) * 1024 + chBase + tt] = V;
        }
    }
}

// -------- scan_all: per-chunk carry prefix (recomputed, L3-resident) + apply --------
__global__ __launch_bounds__(256) void scan_all(
    const unsigned int* __restrict__ CVg, const float* __restrict__ CC,
    const float* __restrict__ CV, const float* __restrict__ h0, float* __restrict__ out)
{
    int g = blockIdx.x * 256 + threadIdx.x;   // 524288
    int ch = g & 1023, ck = (g >> 10) & 63, b = g >> 16;
    float h = h0[b * 1024 + ch];
    const float* pc = CC + (size_t)b * 65536 + ch;
    const float* pv = CV + (size_t)b * 65536 + ch;
#pragma unroll 4
    for (int k = 0; k < ck; ++k)                   // ck block-uniform; CC/CV L3-resident
        h = pc[k * 1024] * h + pv[k * 1024];
    int mbase = b * 4096 + ck * CLEN;
    const unsigned int* p = CVg + (size_t)mbase * 1024 + ch;
    float* po = out + (size_t)mbase * 1024 + ch;
#pragma unroll 8
    for (int i = 0; i < CLEN; ++i) {
        unsigned int u = p[i * 1024];
        h = bf2f((unsigned short)(u & 0xffff)) * h + bf2f((unsigned short)(u >> 16));
        po[i * 1024] = h;
    }
}

extern "C" void kernel_launch(void* const* d_in, const int* in_sizes, int n_in,
                              void* d_out, int out_size, void* d_ws, size_t ws_size,
                              hipStream_t stream)
{
    const float* x    = (const float*)d_in[0];   // (8,4096,1024)
    const float* h0   = (const float*)d_in[1];   // (8,1,1024)
    const float* W    = (const float*)d_in[2];   // (2048,1024)
    const float* bias = (const float*)d_in[3];   // (2048,)
    float* out = (float*)d_out;

    unsigned short* xb = (unsigned short*)d_out;                    // 67MB staged in d_out
    unsigned short* wbP = (unsigned short*)d_ws;                    // 4MB interleaved W bf16
    unsigned int* CVg = (unsigned int*)((char*)d_ws + 4194304);     // 134MB packed (c,v)
    float* CCc = (float*)((char*)d_ws + 138412032);                 // 2MB
    float* CVc = (float*)((char*)d_ws + 140509184);                 // 2MB

    conv_all<<<2560, 256, 0, stream>>>(x, W, xb, wbP);
    gemm_fused<<<4096, 256, 0, stream>>>(xb, wbP, bias, CVg, CCc, CVc);
    scan_all<<<2048, 256, 0, stream>>>(CVg, CCc, CVc, h0, out);
}